// Round 1
// baseline (88.002 us; speedup 1.0000x reference)
//
#include <hip/hip_runtime.h>

// DotProductDecoder: out[e] = sigmoid( dot(h[src[e]], h[dst[e]]) ), D=256 fp32.
// One 64-lane wave per edge: lane i loads float4 at offset 16*i into each row
// -> one coalesced 1KB read per row per wave. 6-step shfl_xor reduction.
__global__ __launch_bounds__(256) void DotProductDecoder_kernel(
    const float* __restrict__ h,
    const int*   __restrict__ src_idx,
    const int*   __restrict__ dst_idx,
    float*       __restrict__ out,
    int E)
{
    const int lane         = threadIdx.x & 63;
    const int waveInBlock  = threadIdx.x >> 6;
    const int wavesPerBlk  = blockDim.x >> 6;
    const int waveGlobal   = blockIdx.x * wavesPerBlk + waveInBlock;
    const int totalWaves   = gridDim.x * wavesPerBlk;

    for (int e = waveGlobal; e < E; e += totalWaves) {
        const int s = src_idx[e];
        const int d = dst_idx[e];
        const float4 a = *reinterpret_cast<const float4*>(h + (size_t)s * 256 + lane * 4);
        const float4 b = *reinterpret_cast<const float4*>(h + (size_t)d * 256 + lane * 4);
        float acc = a.x * b.x + a.y * b.y + a.z * b.z + a.w * b.w;

        // 64-lane butterfly reduction
        #pragma unroll
        for (int off = 32; off >= 1; off >>= 1)
            acc += __shfl_xor(acc, off, 64);

        if (lane == 0) {
            out[e] = 1.0f / (1.0f + __expf(-acc));
        }
    }
}

extern "C" void kernel_launch(void* const* d_in, const int* in_sizes, int n_in,
                              void* d_out, int out_size, void* d_ws, size_t ws_size,
                              hipStream_t stream) {
    const float* h   = (const float*)d_in[0];
    const int*   ei  = (const int*)d_in[1];   // [2, E] row-major: src then dst
    float*       out = (float*)d_out;

    const int E = in_sizes[1] / 2;            // 300000
    const int* src = ei;
    const int* dst = ei + E;

    const int block = 256;                    // 4 waves/block
    const int grid  = 2048;                   // 8192 waves, grid-stride

    DotProductDecoder_kernel<<<grid, block, 0, stream>>>(h, src, dst, out, E);
}

// Round 2
// 64.473 us; speedup vs baseline: 1.3649x; 1.3649x over previous
//
#include <hip/hip_runtime.h>
#include <hip/hip_fp16.h>

// DotProductDecoder: out[e] = sigmoid( dot(h[src[e]], h[dst[e]]) ), D=256.
// Random gather is beyond-L2-BW bound (~3.45 TB/s measured) -> halve gathered
// bytes by converting h to fp16 in d_ws first (sequential stream, cheap),
// then gather 512B rows (one dwordx2 per lane per row, one wave per edge).

__global__ __launch_bounds__(256) void convert_f32_to_f16(
    const float* __restrict__ h, __half* __restrict__ hh, int n4)
{
    int i = blockIdx.x * blockDim.x + threadIdx.x;
    const int stride = gridDim.x * blockDim.x;
    for (; i < n4; i += stride) {
        float4 a = reinterpret_cast<const float4*>(h)[i];
        __half2 p[2];
        p[0] = __floats2half2_rn(a.x, a.y);
        p[1] = __floats2half2_rn(a.z, a.w);
        reinterpret_cast<uint2*>(hh)[i] = *reinterpret_cast<uint2*>(p);
    }
}

__global__ __launch_bounds__(256) void gather_dot_f16(
    const __half* __restrict__ hh,
    const int*    __restrict__ src_idx,
    const int*    __restrict__ dst_idx,
    float*        __restrict__ out,
    int E)
{
    const int lane       = threadIdx.x & 63;
    const int wave       = (blockIdx.x * blockDim.x + threadIdx.x) >> 6;
    const int totalWaves = (gridDim.x * blockDim.x) >> 6;

    for (int e = wave; e < E; e += totalWaves) {
        const int s = src_idx[e];
        const int d = dst_idx[e];
        // row = 256 halves = 512B; lane i reads 8B at byte offset 8*i.
        uint2 ua = *reinterpret_cast<const uint2*>(hh + (size_t)s * 256 + lane * 4);
        uint2 ub = *reinterpret_cast<const uint2*>(hh + (size_t)d * 256 + lane * 4);
        float2 a0 = __half22float2(*reinterpret_cast<__half2*>(&ua.x));
        float2 a1 = __half22float2(*reinterpret_cast<__half2*>(&ua.y));
        float2 b0 = __half22float2(*reinterpret_cast<__half2*>(&ub.x));
        float2 b1 = __half22float2(*reinterpret_cast<__half2*>(&ub.y));
        float acc = a0.x * b0.x + a0.y * b0.y + a1.x * b1.x + a1.y * b1.y;

        #pragma unroll
        for (int off = 32; off >= 1; off >>= 1)
            acc += __shfl_xor(acc, off, 64);

        if (lane == 0) out[e] = 1.0f / (1.0f + __expf(-acc));
    }
}

// fp32 fallback (used only if ws_size is too small for the fp16 copy of h).
__global__ __launch_bounds__(256) void gather_dot_f32(
    const float* __restrict__ h,
    const int*   __restrict__ src_idx,
    const int*   __restrict__ dst_idx,
    float*       __restrict__ out,
    int E)
{
    const int lane       = threadIdx.x & 63;
    const int wave       = (blockIdx.x * blockDim.x + threadIdx.x) >> 6;
    const int totalWaves = (gridDim.x * blockDim.x) >> 6;

    for (int e = wave; e < E; e += totalWaves) {
        const int s = src_idx[e];
        const int d = dst_idx[e];
        const float4 a = *reinterpret_cast<const float4*>(h + (size_t)s * 256 + lane * 4);
        const float4 b = *reinterpret_cast<const float4*>(h + (size_t)d * 256 + lane * 4);
        float acc = a.x * b.x + a.y * b.y + a.z * b.z + a.w * b.w;
        #pragma unroll
        for (int off = 32; off >= 1; off >>= 1)
            acc += __shfl_xor(acc, off, 64);
        if (lane == 0) out[e] = 1.0f / (1.0f + __expf(-acc));
    }
}

extern "C" void kernel_launch(void* const* d_in, const int* in_sizes, int n_in,
                              void* d_out, int out_size, void* d_ws, size_t ws_size,
                              hipStream_t stream) {
    const float* h   = (const float*)d_in[0];
    const int*   ei  = (const int*)d_in[1];   // [2, E]: src row then dst row
    float*       out = (float*)d_out;

    const int ND = in_sizes[0];               // N * 256
    const int E  = in_sizes[1] / 2;
    const int* src = ei;
    const int* dst = ei + E;

    const size_t needed = (size_t)ND * sizeof(__half);

    if (ws_size >= needed) {
        __half* hh = (__half*)d_ws;
        const int n4 = ND / 4;
        convert_f32_to_f16<<<2048, 256, 0, stream>>>(h, hh, n4);
        gather_dot_f16<<<2048, 256, 0, stream>>>(hh, src, dst, out, E);
    } else {
        gather_dot_f32<<<2048, 256, 0, stream>>>(h, src, dst, out, E);
    }
}

// Round 3
// 63.793 us; speedup vs baseline: 1.3795x; 1.0107x over previous
//
#include <hip/hip_runtime.h>
#include <hip/hip_fp16.h>

// DotProductDecoder: out[e] = sigmoid( dot(h[src[e]], h[dst[e]]) ), D=256.
// Stage 1: convert h to fp16 in d_ws (halves gathered bytes).
// Stage 2: half-wave gather: lanes 0-31 load src row (16B/lane), lanes 32-63
//          load dst row; 4 edges in flight per wave-iteration for MLP.

__global__ __launch_bounds__(256) void convert_f32_to_f16(
    const float* __restrict__ h, __half* __restrict__ hh, int n8)
{
    int i = blockIdx.x * blockDim.x + threadIdx.x;
    const int stride = gridDim.x * blockDim.x;
    for (; i < n8; i += stride) {
        float4 a = reinterpret_cast<const float4*>(h)[2 * i + 0];
        float4 b = reinterpret_cast<const float4*>(h)[2 * i + 1];
        __half2 p[4];
        p[0] = __floats2half2_rn(a.x, a.y);
        p[1] = __floats2half2_rn(a.z, a.w);
        p[2] = __floats2half2_rn(b.x, b.y);
        p[3] = __floats2half2_rn(b.z, b.w);
        reinterpret_cast<uint4*>(hh)[i] = *reinterpret_cast<uint4*>(p);
    }
}

__global__ __launch_bounds__(256) void gather_dot_f16(
    const __half* __restrict__ hh,
    const int*    __restrict__ src_idx,
    const int*    __restrict__ dst_idx,
    float*        __restrict__ out,
    int E)
{
    const int lane   = threadIdx.x & 63;
    const int half   = lane >> 5;     // 0: src row, 1: dst row
    const int sub    = lane & 31;     // 16B chunk within row (32 x 16B = 512B)
    const int wave   = (blockIdx.x * blockDim.x + threadIdx.x) >> 6;
    const int nwaves = (gridDim.x * blockDim.x) >> 6;

    for (int base = wave * 4; base < E; base += nwaves * 4) {
        const int n = (E - base < 4) ? (E - base) : 4;

        uint4 v[4];
        // issue all row loads first (up to 4 x 16B per lane in flight)
        #pragma unroll
        for (int k = 0; k < 4; ++k) {
            if (k < n) {
                const int e   = base + k;
                const int idx = half ? dst_idx[e] : src_idx[e];
                v[k] = *reinterpret_cast<const uint4*>(
                    hh + (size_t)idx * 256 + sub * 8);
            }
        }

        #pragma unroll
        for (int k = 0; k < 4; ++k) {
            if (k >= n) break;
            // fetch the opposite row's matching 16B from the other half-wave
            uint4 w;
            w.x = __shfl_xor(v[k].x, 32, 64);
            w.y = __shfl_xor(v[k].y, 32, 64);
            w.z = __shfl_xor(v[k].z, 32, 64);
            w.w = __shfl_xor(v[k].w, 32, 64);

            const __half2* pa = reinterpret_cast<const __half2*>(&v[k]);
            const __half2* pb = reinterpret_cast<const __half2*>(&w);
            float acc = 0.0f;
            #pragma unroll
            for (int j = 0; j < 4; ++j) {
                float2 fa = __half22float2(pa[j]);
                float2 fb = __half22float2(pb[j]);
                acc += fa.x * fb.x + fa.y * fb.y;
            }
            // reduce across the 32 chunk-lanes (both halves hold same products)
            #pragma unroll
            for (int off = 16; off >= 1; off >>= 1)
                acc += __shfl_xor(acc, off, 64);

            if (lane == 0)
                out[base + k] = 1.0f / (1.0f + __expf(-acc));
        }
    }
}

// fp32 fallback if workspace can't hold the fp16 table.
__global__ __launch_bounds__(256) void gather_dot_f32(
    const float* __restrict__ h,
    const int*   __restrict__ src_idx,
    const int*   __restrict__ dst_idx,
    float*       __restrict__ out,
    int E)
{
    const int lane   = threadIdx.x & 63;
    const int wave   = (blockIdx.x * blockDim.x + threadIdx.x) >> 6;
    const int nwaves = (gridDim.x * blockDim.x) >> 6;
    for (int e = wave; e < E; e += nwaves) {
        const int s = src_idx[e];
        const int d = dst_idx[e];
        const float4 a = *reinterpret_cast<const float4*>(h + (size_t)s * 256 + lane * 4);
        const float4 b = *reinterpret_cast<const float4*>(h + (size_t)d * 256 + lane * 4);
        float acc = a.x * b.x + a.y * b.y + a.z * b.z + a.w * b.w;
        #pragma unroll
        for (int off = 32; off >= 1; off >>= 1)
            acc += __shfl_xor(acc, off, 64);
        if (lane == 0) out[e] = 1.0f / (1.0f + __expf(-acc));
    }
}

extern "C" void kernel_launch(void* const* d_in, const int* in_sizes, int n_in,
                              void* d_out, int out_size, void* d_ws, size_t ws_size,
                              hipStream_t stream) {
    const float* h   = (const float*)d_in[0];
    const int*   ei  = (const int*)d_in[1];   // [2, E]: src row then dst row
    float*       out = (float*)d_out;

    const int ND = in_sizes[0];               // N * 256
    const int E  = in_sizes[1] / 2;
    const int* src = ei;
    const int* dst = ei + E;

    const size_t needed = (size_t)ND * sizeof(__half);

    if (ws_size >= needed) {
        __half* hh = (__half*)d_ws;
        const int n8 = ND / 8;
        convert_f32_to_f16<<<2048, 256, 0, stream>>>(h, hh, n8);
        gather_dot_f16<<<2048, 256, 0, stream>>>(hh, src, dst, out, E);
    } else {
        gather_dot_f32<<<2048, 256, 0, stream>>>(h, src, dst, out, E);
    }
}